// Round 8
// baseline (275.469 us; speedup 1.0000x reference)
//
#include <hip/hip_runtime.h>
#include <hip/hip_bf16.h>

// out = x @ (qw*scale)^T + b  => GEMM M=8192, N=8192, K=2048, bf16 MFMA.
// R8: register-double-buffered A-fragments (af0/af1 alternate per phase;
// MFMA(p) uses frags read at p-1) + barriers only at odd phases (4/iter).
// Odd phase: {vmcnt(6); barrier; af-read(next); stage; MFMA}. Even phase:
// {bf-read(this); af-read(next); stage; MFMA} - no barrier. Full WAR/RAW
// ledger re-verified (see stage-map comment). Swizzle/stage/epilogue from
// R7 (0 conflicts). bf single-buffered (no liveness overlap).

#define M_DIM 8192
#define N_DIM 8192
#define K_DIM 2048
#define NT    (K_DIM / 64)   // 32 K-tiles (BK=64), 2 per iteration

typedef __attribute__((ext_vector_type(8))) short bf16x8;
typedef __attribute__((ext_vector_type(4))) float f32x4;

__device__ __forceinline__ ushort f2bf(float f) {
    union { float f; unsigned int u; } v; v.f = f;
    unsigned int u = v.u;
    return (ushort)((u + 0x7fffu + ((u >> 16) & 1u)) >> 16);  // RNE
}

// Fused convert: chunks [0, n4) = x (fp32->bf16), [n4, 2*n4) = w (int->bf16).
__global__ void cvt_kernel(const float* __restrict__ x, const int* __restrict__ w,
                           ushort* __restrict__ xb, ushort* __restrict__ wb, int n4) {
    int i = blockIdx.x * blockDim.x + threadIdx.x;
    if (i < n4) {
        const float4 v = reinterpret_cast<const float4*>(x)[i];
        ushort4 r;
        r.x = f2bf(v.x); r.y = f2bf(v.y); r.z = f2bf(v.z); r.w = f2bf(v.w);
        reinterpret_cast<ushort4*>(xb)[i] = r;
    } else {
        int j = i - n4;
        const int4 v = reinterpret_cast<const int4*>(w)[j];
        ushort4 r;
        r.x = f2bf((float)v.x); r.y = f2bf((float)v.y);
        r.z = f2bf((float)v.z); r.w = f2bf((float)v.w);
        reinterpret_cast<ushort4*>(wb)[j] = r;
    }
}

// Piece = [256 rows][32 k] bf16 = 16 KiB. lds[buf][op][kh]. Stage map
// (iter i, tiles t=2i buf0 / t+1 buf1), stages s0..s7 at phases p0..p7:
//  s0:(1,A,kh1)<-t+1  s1:(1,B,kh1)<-t+1  s2:(0,A,kh0)<-t+2  s3:(0,B,kh0)<-t+2
//  s4:(0,A,kh1)<-t+2  s5:(0,B,kh1)<-t+2  s6:(1,A,kh0)<-t+3  s7:(1,B,kh0)<-t+3
// MFMA data: d0/d1=buf0kh0(mh0/1), d2/d3=buf0kh1, d4/d5=buf1kh0, d6/d7=buf1kh1.
// af(d_{p+1}) is read at phase p (into the alternate set); bf(d_p) read at
// even phase p. vmcnt(6) at odd p (before barrier) retires: p1 -> thru prev
// s5; p3 -> prev s7; p5 -> s1; p7 -> s3 == exactly the pieces the next reads
// need; the barrier then makes all waves' retirements visible (cross-wave).
// WAR: each stage has >=1 odd-phase barrier after its piece's last old reader
// (checked per piece: s0..s7 all OK). Tail drains: 6/4/0.
__global__ __launch_bounds__(512, 2) void gemm_bf16_kernel(
    const ushort* __restrict__ A,   // [M][K] bf16
    const ushort* __restrict__ B,   // [N][K] bf16
    const float* __restrict__ scale_p,
    const float* __restrict__ bias,
    float* __restrict__ C)          // [M][N] fp32
{
    __shared__ __align__(16) ushort lds[2][2][2][8192];

    const int tid  = threadIdx.x;
    const int lane = tid & 63;
    const int wave = tid >> 6;
    const int wr = wave >> 2;        // 0..1 (128-row M half)
    const int wc = wave & 3;         // 0..3 (64-col N quarter)
    const int bm = blockIdx.y;
    const int bn = blockIdx.x;

    const ushort* gA = A + (size_t)(bm * 256) * K_DIM;
    const ushort* gB = B + (size_t)(bn * 256) * K_DIM;

    const int sr = tid >> 2;                       // 0..127
    const int sg = (tid & 3) ^ ((tid >> 3) & 3);   // pre-swizzled source granule
    const ushort* sA0 = gA + (size_t)sr * K_DIM + sg * 8;
    const ushort* sA1 = gA + (size_t)(sr + 128) * K_DIM + sg * 8;
    const ushort* sB0 = gB + (size_t)sr * K_DIM + sg * 8;
    const ushort* sB1 = gB + (size_t)(sr + 128) * K_DIM + sg * 8;

#define GLDS(src, dst) __builtin_amdgcn_global_load_lds( \
    (const __attribute__((address_space(1))) unsigned int*)(src), \
    (__attribute__((address_space(3))) unsigned int*)(dst), 16, 0, 0)

#define STAGE_P(buf, op, kh, kt) do { \
    const int _c = (kt) * 64 + (kh) * 32; \
    GLDS(((op) ? sB0 : sA0) + _c, &lds[buf][op][kh][tid * 8]); \
    GLDS(((op) ? sB1 : sA1) + _c, &lds[buf][op][kh][tid * 8 + 4096]); \
} while (0)

    f32x4 acc[8][4];
#pragma unroll
    for (int m = 0; m < 8; ++m)
#pragma unroll
        for (int n = 0; n < 4; ++n)
            acc[m][n] = (f32x4){0.f, 0.f, 0.f, 0.f};

    const int lr   = lane & 15;
    const int swzC = ((lane >> 4) ^ ((lane >> 1) & 3)) << 4;
    const int offA = (wr * 128 + lr) * 64 + swzC;   // + mh*4096 + m*1024
    const int offB = (wc * 64  + lr) * 64 + swzC;   // + n*1024

    bf16x8 af0[4], af1[4], bfr[4];

#define DS_AF(dst, buf, kh, mh) do { \
    const char* _p = (const char*)&lds[buf][0][kh][0] + offA + (mh) * 4096; \
    dst[0] = *(const bf16x8*)(_p);        dst[1] = *(const bf16x8*)(_p + 1024); \
    dst[2] = *(const bf16x8*)(_p + 2048); dst[3] = *(const bf16x8*)(_p + 3072); \
} while (0)

#define DS_BF(buf, kh) do { \
    const char* _p = (const char*)&lds[buf][1][kh][0] + offB; \
    bfr[0] = *(const bf16x8*)(_p);        bfr[1] = *(const bf16x8*)(_p + 1024); \
    bfr[2] = *(const bf16x8*)(_p + 2048); bfr[3] = *(const bf16x8*)(_p + 3072); \
} while (0)

#define MFMA16(src, mh) do { \
    _Pragma("unroll") \
    for (int _m = 0; _m < 4; ++_m) \
        _Pragma("unroll") \
        for (int _n = 0; _n < 4; ++_n) \
            acc[(mh) * 4 + _m][_n] = __builtin_amdgcn_mfma_f32_16x16x32_bf16( \
                src[_m], bfr[_n], acc[(mh) * 4 + _m][_n], 0, 0, 0); \
} while (0)

#define BARRIER() do { __builtin_amdgcn_s_barrier(); asm volatile("" ::: "memory"); } while (0)
#define VMC(N)   asm volatile("s_waitcnt vmcnt(" #N ")" ::: "memory")

// Even phase: bf(this) + af(next)->alt, stage, MFMA(this) with af loaded at p-1.
#define PH_E(bufR, khR, bufN, khN, STG) do { \
    DS_BF(bufR, khR); \
    DS_AF(af1, bufN, khN, 1); \
    STG; \
    __builtin_amdgcn_s_setprio(1); MFMA16(af0, 0); __builtin_amdgcn_s_setprio(0); \
} while (0)
// note: at even phase, next data = same buf/kh, mh1 -> (bufN,khN)==(bufR,khR)

// Odd phase: vmcnt; barrier; af(next even data)->af0; stage; MFMA(this, af1).
#define PH_O(bufN, khN, STG, VM) do { \
    VM; \
    BARRIER(); \
    DS_AF(af0, bufN, khN, 0); \
    STG; \
    __builtin_amdgcn_s_setprio(1); MFMA16(af1, 1); __builtin_amdgcn_s_setprio(0); \
} while (0)

    // Prologue: stage 6 pieces (tile0 all 4 + tile1 kh0) = future s2..s7;
    // drain so first 2 pieces (buf0 kh0) retired; barrier; preload af0(d0).
    STAGE_P(0, 0, 0, 0); STAGE_P(0, 1, 0, 0);
    STAGE_P(0, 0, 1, 0); STAGE_P(0, 1, 1, 0);
    STAGE_P(1, 0, 0, 1); STAGE_P(1, 1, 0, 1);
    VMC(8);
    BARRIER();
    DS_AF(af0, 0, 0, 0);

#pragma unroll 1
    for (int i = 0; i < NT / 2 - 1; ++i) {
        const int t = 2 * i;
        PH_E(0, 0, 0, 0, STAGE_P(1, 0, 1, t + 1));                 // p0: MFMA d0
        PH_O(0, 1,       STAGE_P(1, 1, 1, t + 1), VMC(6));         // p1: MFMA d1
        PH_E(0, 1, 0, 1, STAGE_P(0, 0, 0, t + 2));                 // p2: MFMA d2
        PH_O(1, 0,       STAGE_P(0, 1, 0, t + 2), VMC(6));         // p3: MFMA d3
        PH_E(1, 0, 1, 0, STAGE_P(0, 0, 1, t + 2));                 // p4: MFMA d4
        PH_O(1, 1,       STAGE_P(0, 1, 1, t + 2), VMC(6));         // p5: MFMA d5
        PH_E(1, 1, 1, 1, STAGE_P(1, 0, 0, t + 3));                 // p6: MFMA d6
        PH_O(0, 0,       STAGE_P(1, 1, 0, t + 3), VMC(6));         // p7: MFMA d7
    }
    {   // Peeled final iteration (t = NT-2): only tile NT-1's kh1 still stages.
        PH_E(0, 0, 0, 0, STAGE_P(1, 0, 1, NT - 1));                // p0
        PH_O(0, 1,       STAGE_P(1, 1, 1, NT - 1), VMC(6));        // p1
        PH_E(0, 1, 0, 1, (void)0);                                 // p2
        PH_O(1, 0,       (void)0, VMC(4));                         // p3
        PH_E(1, 0, 1, 0, (void)0);                                 // p4
        PH_O(1, 1,       (void)0, VMC(0));                         // p5
        PH_E(1, 1, 1, 1, (void)0);                                 // p6
        // p7: final MFMA only (no next read, no stage, no barrier needed)
        __builtin_amdgcn_s_setprio(1); MFMA16(af1, 1); __builtin_amdgcn_s_setprio(0);
    }

#undef PH_O
#undef PH_E
#undef VMC
#undef BARRIER
#undef MFMA16
#undef DS_BF
#undef DS_AF
#undef STAGE_P
#undef GLDS

    // Epilogue: C/D layout col = lane&15, row = (lane>>4)*4 + j (verified R1-R7)
    const float s = scale_p[0];
#pragma unroll
    for (int n = 0; n < 4; ++n) {
        const int col = bn * 256 + wc * 64 + n * 16 + lr;
        const float bb = bias[col];
#pragma unroll
        for (int m = 0; m < 8; ++m) {
            const int row0 = bm * 256 + wr * 128 + m * 16 + (lane >> 4) * 4;
#pragma unroll
            for (int j = 0; j < 4; ++j)
                C[(size_t)(row0 + j) * N_DIM + col] = acc[m][n][j] * s + bb;
        }
    }
}

// Correctness-insurance fallback if ws_size < 64 MiB (should not trigger).
__global__ void naive_fallback(const float* __restrict__ x, const int* __restrict__ w,
                               const float* __restrict__ scale, const float* __restrict__ bias,
                               float* __restrict__ out) {
    size_t i = (size_t)blockIdx.x * blockDim.x + threadIdx.x;
    int m = (int)(i / N_DIM);
    int n = (int)(i % N_DIM);
    const float* xr = x + (size_t)m * K_DIM;
    const int*   wrw = w + (size_t)n * K_DIM;
    float acc = 0.f;
    for (int k = 0; k < K_DIM; ++k) acc += xr[k] * (float)wrw[k];
    out[i] = acc * scale[0] + bias[n];
}

extern "C" void kernel_launch(void* const* d_in, const int* in_sizes, int n_in,
                              void* d_out, int out_size, void* d_ws, size_t ws_size,
                              hipStream_t stream) {
    const float* x     = (const float*)d_in[0];
    const int*   qw    = (const int*)d_in[1];
    const float* scale = (const float*)d_in[2];
    const float* bias  = (const float*)d_in[3];
    float* out = (float*)d_out;

    const size_t elems = (size_t)M_DIM * K_DIM;          // 16,777,216
    const size_t need  = elems * 2u * sizeof(ushort);    // 64 MiB

    if (ws_size >= need) {
        ushort* xb = (ushort*)d_ws;
        ushort* wb = xb + elems;
        const int n4 = (int)(elems / 4);
        cvt_kernel<<<(2 * n4) / 256, 256, 0, stream>>>(x, qw, xb, wb, n4);
        dim3 grid(N_DIM / 256, M_DIM / 256);
        gemm_bf16_kernel<<<grid, 512, 0, stream>>>(xb, wb, scale, bias, out);
    } else {
        const size_t total = (size_t)M_DIM * N_DIM;
        naive_fallback<<<(int)(total / 256), 256, 0, stream>>>(x, qw, scale, bias, out);
    }
}